// Round 3
// baseline (327.195 us; speedup 1.0000x reference)
//
#include <hip/hip_runtime.h>
#include <hip/hip_bf16.h>

typedef __attribute__((ext_vector_type(8))) short short8;
typedef __attribute__((ext_vector_type(4))) float f32x4;
typedef unsigned short u16;
typedef unsigned int u32;

#define NROWS 16384
#define KDIM 16384
#define EPS 1e-6f

__device__ __forceinline__ u16 f2bf(float x) {
    union { float f; u32 u; } v; v.f = x;
    u32 u = v.u;
    u32 r = (u + 0x7FFFu + ((u >> 16) & 1u)) >> 16;  // RNE
    return (u16)r;
}

__device__ __forceinline__ void glds16(const void* g, void* l) {
    __builtin_amdgcn_global_load_lds(
        (const __attribute__((address_space(1))) void*)g,
        (__attribute__((address_space(3))) void*)l, 16, 0, 0);
}

__device__ __forceinline__ short cvbf(float x) {
    __hip_bfloat16 h = __float2bfloat16(x);
    return *(short*)&h;
}

// ---------------- Stage 0: transpose weight -> Wt[64][256] ----------------
__global__ __launch_bounds__(256) void wt_kernel(const float* __restrict__ W,
                                                 float* __restrict__ Wt) {
    int idx = blockIdx.x * 256 + threadIdx.x;  // 16384
    int k = idx >> 6, c = idx & 63;
    Wt[c * 256 + k] = W[idx];
}

// ---------------- Stage 1: support = input @ W (fp32) ---------------------
__global__ __launch_bounds__(256) void support_kernel(
    const float* __restrict__ inp, const float* __restrict__ Wt,
    float* __restrict__ sup)
{
    int tid = threadIdx.x;
    int col = tid & 63;
    int rr = tid >> 6;                        // 0..3
    int rowbase = blockIdx.x * 32 + rr * 8;   // 8 rows per thread
    const float4* wt4 = (const float4*)(Wt + (size_t)col * 256);
    float acc[8];
#pragma unroll
    for (int i = 0; i < 8; ++i) acc[i] = 0.f;
    for (int k4 = 0; k4 < 64; ++k4) {
        float4 wv = wt4[k4];
#pragma unroll
        for (int i = 0; i < 8; ++i) {
            float4 iv = *((const float4*)(inp + (size_t)(rowbase + i) * 256) + k4);
            acc[i] += iv.x * wv.x + iv.y * wv.y + iv.z * wv.z + iv.w * wv.w;
        }
    }
#pragma unroll
    for (int i = 0; i < 8; ++i)
        sup[(size_t)(rowbase + i) * 64 + col] = acc[i];
}

// ---------------- Stage 2: global min ------------------------------------
__global__ __launch_bounds__(256) void min_part_kernel(
    const float* __restrict__ sup, float* __restrict__ partmin)
{
    __shared__ float wmin[4];
    int tid = threadIdx.x;
    const float4* s4 = (const float4*)sup;
    size_t idx = (size_t)blockIdx.x * 256 + tid;
    float m = 3.4e38f;
#pragma unroll
    for (int j = 0; j < 4; ++j) {
        float4 v = s4[idx + (size_t)j * 65536];
        m = fminf(m, fminf(fminf(v.x, v.y), fminf(v.z, v.w)));
    }
#pragma unroll
    for (int off = 32; off; off >>= 1) m = fminf(m, __shfl_down(m, off, 64));
    if ((tid & 63) == 0) wmin[tid >> 6] = m;
    __syncthreads();
    if (tid == 0)
        partmin[blockIdx.x] = fminf(fminf(wmin[0], wmin[1]), fminf(wmin[2], wmin[3]));
}

__global__ __launch_bounds__(256) void min_final_kernel(
    const float* __restrict__ partmin, float* __restrict__ mu)
{
    __shared__ float wmin[4];
    int tid = threadIdx.x;
    float m = partmin[tid];
#pragma unroll
    for (int off = 32; off; off >>= 1) m = fminf(m, __shfl_down(m, off, 64));
    if ((tid & 63) == 0) wmin[tid >> 6] = m;
    __syncthreads();
    if (tid == 0)
        mu[0] = fminf(fminf(wmin[0], wmin[1]), fminf(wmin[2], wmin[3]));
}

// ---------------- Stage 3: Bt[n][k] bf16; n<64: s^(p+1), n>=64: s^p -------
__global__ __launch_bounds__(256) void build_bt_kernel(
    const float* __restrict__ sup, const float* __restrict__ muptr,
    const int* __restrict__ pptr, u16* __restrict__ Bt)
{
    int k = blockIdx.x * 256 + threadIdx.x;   // 0..16383
    float mu = *muptr;
    int p = *pptr;
    const float4* srow = (const float4*)(sup + (size_t)k * 64);
#pragma unroll
    for (int j = 0; j < 16; ++j) {
        float4 v = srow[j];
        float ss[4] = {v.x, v.y, v.z, v.w};
#pragma unroll
        for (int q = 0; q < 4; ++q) {
            int c = j * 4 + q;
            float s = ss[q] - mu + EPS;
            float d = 1.f;
            for (int i = 0; i < p; ++i) d *= s;   // s^p
            Bt[(size_t)c * KDIM + k] = f2bf(d * s);          // top
            Bt[(size_t)(c + 64) * KDIM + k] = f2bf(d);       // down
        }
    }
}

// ---------------- Stage 4: GEMM partials, K-split=2 -----------------------
// BM=64, BN=128 (64 top | 64 down), BK=64, 512 thr (8 waves, 2M x 4N).
// A reg-staged f32->bf16 (write-late), B via global_load_lds.
// Both tiles bf16 in LDS, XOR-swizzled 16B granules (write & read XORed).
// XCD remap: each XCD owns one K-half -> its 2MB Bt slice is L2-resident.
#define BM 64
#define BN 128
#define BK 64
#define KH 8192
#define NTI 128   // KH/BK

__global__ __launch_bounds__(512, 4) void gemm_kernel(
    const float* __restrict__ adj, const u16* __restrict__ Bt,
    float* __restrict__ Pp)
{
    __shared__ __align__(16) u16 Ash[2][BM * BK];   //  8 KB x2 (bf16)
    __shared__ __align__(16) u16 Bsh[2][BN * BK];   // 16 KB x2 (bf16)

    const int tid = threadIdx.x;
    const int P = blockIdx.x;
    const int L = (P & 7) * 64 + (P >> 3);   // bijective XCD-chunked remap
    const int h  = L >> 8;                   // XCDs 0-3: h=0, XCDs 4-7: h=1
    const int rb = L & 255;
    const size_t rowbase = (size_t)rb * BM;
    const size_t kbase   = (size_t)h * KH;

    // --- A staging (reg -> cvt -> LDS): thread = (row, 8-float chunk)
    const int ars = tid >> 3;               // 0..63 : A row
    const int ac8 = tid & 7;                // 0..7  : chunk of 8 floats
    const float* asrc = adj + (rowbase + ars) * KDIM + kbase + ac8 * 8;
    const int awoff = ars * 8 + (ac8 ^ (ars & 7));   // swizzled granule idx

    // --- B staging (global_load_lds, linear dest + inverse-swizzled src)
    const int ga0 = tid, ga1 = tid + 512;
    const int bn0 = ga0 >> 3, bx0 = (ga0 & 7) ^ (bn0 & 7);
    const int bn1 = ga1 >> 3, bx1 = (ga1 & 7) ^ (bn1 & 7);
    const u16* bsrc0 = Bt + (size_t)bn0 * KDIM + kbase + bx0 * 8;
    const u16* bsrc1 = Bt + (size_t)bn1 * KDIM + kbase + bx1 * 8;

    // --- compute indices: 8 waves = 2M x 4N
    const int lane = tid & 63;
    const int w    = tid >> 6;
    const int wm   = w >> 2;                // 0..1 : 32-row half
    const int wn   = w & 3;                 // 0..3 : 16-col group
    const int l15  = lane & 15, lg = lane >> 4;
    const int arow0 = wm * 32 + l15;        // frag rows
    const int arow1 = arow0 + 16;
    const int nt = wn * 16 + l15;           // top col
    const int nd = nt + 64;                 // down col
    const int asw = arow0 & 7;              // == arow1 & 7
    const int bsw = nt & 7;                 // == nd & 7

    f32x4 acc00 = {0.f, 0.f, 0.f, 0.f};
    f32x4 acc01 = acc00, acc10 = acc00, acc11 = acc00;

    float4 ra0, ra1;

    auto issueA = [&](int kt) {
        const float4* ap = (const float4*)(asrc + kt * BK);
        ra0 = ap[0]; ra1 = ap[1];
    };
    auto issueB = [&](int kt, int buf) {
        char* bb = (char*)Bsh[buf];
        const int koff = kt * BK;
        glds16(bsrc0 + koff, bb + ga0 * 16);
        glds16(bsrc1 + koff, bb + ga1 * 16);
    };
    auto writeA = [&](int buf) {
        uint4 awv;
        awv.x = (u32)(u16)cvbf(ra0.x) | ((u32)(u16)cvbf(ra0.y) << 16);
        awv.y = (u32)(u16)cvbf(ra0.z) | ((u32)(u16)cvbf(ra0.w) << 16);
        awv.z = (u32)(u16)cvbf(ra1.x) | ((u32)(u16)cvbf(ra1.y) << 16);
        awv.w = (u32)(u16)cvbf(ra1.z) | ((u32)(u16)cvbf(ra1.w) << 16);
        ((uint4*)Ash[buf])[awoff] = awv;
    };

    // prologue: tile 0
    issueA(0);
    issueB(0, 0);
    writeA(0);          // compiler inserts counted vmcnt for ra*

    for (int t = 0; t < NTI; ++t) {
        __syncthreads();            // buf[t&1] ready (A ds_write + B vmcnt)
        const int nb = (t + 1) & 1;
        if (t + 1 < NTI) {
            issueA(t + 1);          // HBM loads in flight during compute
            issueB(t + 1, nb);
        }
        const short8* As8 = (const short8*)Ash[t & 1];
        const short8* Bs8 = (const short8*)Bsh[t & 1];
#pragma unroll
        for (int ks = 0; ks < 2; ++ks) {
            const int g = ks * 4 + lg;
            short8 a0 = As8[arow0 * 8 + (g ^ asw)];
            short8 a1 = As8[arow1 * 8 + (g ^ asw)];
            short8 b0 = Bs8[nt * 8 + (g ^ bsw)];
            short8 b1 = Bs8[nd * 8 + (g ^ bsw)];
            acc00 = __builtin_amdgcn_mfma_f32_16x16x32_bf16(a0, b0, acc00, 0, 0, 0);
            acc01 = __builtin_amdgcn_mfma_f32_16x16x32_bf16(a0, b1, acc01, 0, 0, 0);
            acc10 = __builtin_amdgcn_mfma_f32_16x16x32_bf16(a1, b0, acc10, 0, 0, 0);
            acc11 = __builtin_amdgcn_mfma_f32_16x16x32_bf16(a1, b1, acc11, 0, 0, 0);
        }
        if (t + 1 < NTI) writeA(nb);   // write-late: loads had full compute phase
    }

    // partial store: [block L][64 rows][128 cols]; C: col=l15, row=lg*4+q
    float* pb = Pp + (size_t)L * (BM * BN);
#pragma unroll
    for (int q = 0; q < 4; ++q) {
        int r0 = wm * 32 + lg * 4 + q;
        int r1 = r0 + 16;
        pb[r0 * BN + nt] = acc00[q];
        pb[r0 * BN + nd] = acc01[q];
        pb[r1 * BN + nt] = acc10[q];
        pb[r1 * BN + nd] = acc11[q];
    }
}

// ---------------- Stage 5: combine K-halves, ratio + mu + bias ------------
// Pp logical layout: [h][rb 0..255][64][128]  (L = h*256 + rb)
__global__ __launch_bounds__(256) void reduce_kernel(
    const float* __restrict__ Pp, const float* __restrict__ bias,
    const float* __restrict__ muptr, float* __restrict__ out)
{
    int idx = blockIdx.x * 256 + threadIdx.x;   // 1M outputs
    int r = idx >> 6, c = idx & 63;
    int rb = r >> 6, rr = r & 63;
    const float* p0 = Pp + (size_t)rb * (BM * BN) + rr * BN + c;
    const float* p1 = p0 + (size_t)256 * (BM * BN);
    float T = p0[0]  + p1[0];
    float D = p0[64] + p1[64];
    out[idx] = T / D + muptr[0] + bias[c];
}

extern "C" void kernel_launch(void* const* d_in, const int* in_sizes, int n_in,
                              void* d_out, int out_size, void* d_ws, size_t ws_size,
                              hipStream_t stream)
{
    const float* inp  = (const float*)d_in[0];
    const float* adj  = (const float*)d_in[1];
    const float* W    = (const float*)d_in[2];
    const float* bias = (const float*)d_in[3];
    const int*   p    = (const int*)d_in[4];
    float* out = (float*)d_out;

    // ws layout: Bt 4MB | partmin 1KB | mu | Wt 64KB | (8MB:) Pp 16MB
    char* ws = (char*)d_ws;
    u16*   Bt      = (u16*)ws;
    float* partmin = (float*)(ws + (size_t)4 * 1024 * 1024);
    float* mu      = partmin + 256;
    float* Wt      = (float*)(ws + (size_t)4 * 1024 * 1024 + 4096);
    float* Pp      = (float*)(ws + (size_t)8 * 1024 * 1024);

    float* sup = out;   // park support in d_out; reduce overwrites at the end

    wt_kernel       <<<64,   256, 0, stream>>>(W, Wt);
    support_kernel  <<<512,  256, 0, stream>>>(inp, Wt, sup);
    min_part_kernel <<<256,  256, 0, stream>>>(sup, partmin);
    min_final_kernel<<<1,    256, 0, stream>>>(partmin, mu);
    build_bt_kernel <<<64,   256, 0, stream>>>(sup, mu, p, Bt);
    gemm_kernel     <<<512,  512, 0, stream>>>(adj, Bt, Pp);
    reduce_kernel   <<<4096, 256, 0, stream>>>(Pp, bias, mu, out);
}